// Round 1
// baseline (321.262 us; speedup 1.0000x reference)
//
#include <hip/hip_runtime.h>
#include <math.h>

#define D 256
#define H 512      // 2*D
#define TT 10
#define THRESH 0.4f
#define JT 64      // rows per block in gate kernel

// ---------------------------------------------------------------------------
// K1: fused gate MLP: sigmoid( relu(h_sub @ W1 + b1) @ W2 + b2 )
// grid: S/JT blocks, 256 threads, 64 KB dynamic LDS
// ---------------------------------------------------------------------------
__global__ __launch_bounds__(256) void gate_kernel(
    const float* __restrict__ h_sub,   // [S][D]
    const float* __restrict__ W1,      // [D][H]
    const float* __restrict__ b1,      // [H]
    const float* __restrict__ W2,      // [H]
    const float* __restrict__ b2,      // [1]
    float* __restrict__ submask)       // [S]
{
    extern __shared__ float xs[];      // [JT][D] = 64*256 floats = 64 KB
    const int tid = threadIdx.x;
    const int jbase = blockIdx.x * JT;

    // stage 64 rows of h_sub, coalesced float4
    #pragma unroll
    for (int it = 0; it < 16; ++it) {
        int idx = it * 256 + tid;          // float4 index in [0, 4096)
        int r = idx >> 6;                  // row 0..63
        int c = (idx & 63) << 2;           // col 0..252
        float4 v = *reinterpret_cast<const float4*>(
            h_sub + (size_t)(jbase + r) * D + c);
        *reinterpret_cast<float4*>(&xs[r * D + c]) = v;
    }
    __syncthreads();

    const int kk = (tid & 31) << 2;        // k offset within 128-col tile
    const int jg = tid >> 5;               // 0..7  -> rows jg*8 .. jg*8+7
    float lp[8];
    #pragma unroll
    for (int a = 0; a < 8; ++a) lp[a] = 0.f;

    for (int kt = 0; kt < H; kt += 128) {
        const int k = kt + kk;
        float acc[8][4];
        #pragma unroll
        for (int a = 0; a < 8; ++a)
            #pragma unroll
            for (int b = 0; b < 4; ++b) acc[a][b] = 0.f;

        for (int d = 0; d < D; d += 4) {
            float w4[4][4];
            #pragma unroll
            for (int i = 0; i < 4; ++i)
                *reinterpret_cast<float4*>(w4[i]) =
                    *reinterpret_cast<const float4*>(W1 + (size_t)(d + i) * H + k);
            #pragma unroll
            for (int a = 0; a < 8; ++a) {
                float x4[4];
                *reinterpret_cast<float4*>(x4) =
                    *reinterpret_cast<const float4*>(&xs[(jg * 8 + a) * D + d]);
                #pragma unroll
                for (int i = 0; i < 4; ++i)
                    #pragma unroll
                    for (int b = 0; b < 4; ++b)
                        acc[a][b] = fmaf(x4[i], w4[i][b], acc[a][b]);
            }
        }

        float b14[4], w24[4];
        *reinterpret_cast<float4*>(b14) = *reinterpret_cast<const float4*>(b1 + k);
        *reinterpret_cast<float4*>(w24) = *reinterpret_cast<const float4*>(W2 + k);
        #pragma unroll
        for (int a = 0; a < 8; ++a) {
            float s = 0.f;
            #pragma unroll
            for (int b = 0; b < 4; ++b) {
                float hv = acc[a][b] + b14[b];
                hv = hv > 0.f ? hv : 0.f;
                s = fmaf(hv, w24[b], s);
            }
            lp[a] += s;
        }
    }

    // reduce over the 32 lanes sharing a j-group (contiguous within wave half)
    #pragma unroll
    for (int m = 1; m < 32; m <<= 1)
        #pragma unroll
        for (int a = 0; a < 8; ++a) lp[a] += __shfl_xor(lp[a], m);

    if ((tid & 31) == 0) {
        const float bb = b2[0];
        #pragma unroll
        for (int a = 0; a < 8; ++a) {
            float logit = lp[a] + bb;
            float sig = 1.0f / (1.0f + expf(-logit));
            submask[jbase + jg * 8 + a] = sig;
        }
    }
}

// ---------------------------------------------------------------------------
// K2: per-graph masked segment mean + cosine + classifier logits
// grid: B blocks, 256 threads (4 waves); wave w scans S/4 of the mask row
// ---------------------------------------------------------------------------
__global__ __launch_bounds__(256) void seg_kernel(
    const float* __restrict__ h_graph,  // [B][D]
    const float* __restrict__ h_sub,    // [S][D]
    const int*   __restrict__ mask,     // [B][S]
    const float* __restrict__ submask,  // [S]
    const float* __restrict__ Wc,       // [2D][TT]
    const float* __restrict__ bc,       // [TT]
    float* __restrict__ logits,         // [B][TT]
    float* __restrict__ cos_ws,         // [B]
    int S)
{
    const int i = blockIdx.x;
    const int tid = threadIdx.x;
    const int lane = tid & 63;
    const int w = tid >> 6;
    const int* mrow = mask + (size_t)i * S;

    float4 acc = make_float4(0.f, 0.f, 0.f, 0.f);
    int cnt = 0;

    const int per = S >> 2;     // elements per wave
    for (int base = w * per; base < (w + 1) * per; base += 256) {
        const int j0 = base + (lane << 2);
        int4 m4 = *reinterpret_cast<const int4*>(mrow + j0);
        unsigned long long bal[4];
        bal[0] = __ballot((m4.x != 0) & (submask[j0 + 0] > THRESH));
        bal[1] = __ballot((m4.y != 0) & (submask[j0 + 1] > THRESH));
        bal[2] = __ballot((m4.z != 0) & (submask[j0 + 2] > THRESH));
        bal[3] = __ballot((m4.w != 0) & (submask[j0 + 3] > THRESH));
        #pragma unroll
        for (int s = 0; s < 4; ++s) {
            unsigned long long b = bal[s];
            while (b) {
                int t = __builtin_ctzll(b);
                b &= b - 1;
                int jj = base + (t << 2) + s;
                float4 hv = *reinterpret_cast<const float4*>(
                    h_sub + (size_t)jj * D + (lane << 2));
                acc.x += hv.x; acc.y += hv.y; acc.z += hv.z; acc.w += hv.w;
                cnt++;
            }
        }
    }

    __shared__ float ssum[4][D];
    __shared__ int   scnt[4];
    *reinterpret_cast<float4*>(&ssum[w][lane << 2]) = acc;
    if (lane == 0) scnt[w] = cnt;
    __syncthreads();

    // thread tid owns component d = tid
    float a = ssum[0][tid] + ssum[1][tid] + ssum[2][tid] + ssum[3][tid];
    const int c = scnt[0] + scnt[1] + scnt[2] + scnt[3];
    a = (c > 0) ? (a / (float)c) : 0.f;
    const float g = h_graph[(size_t)i * D + tid];

    // block reductions for ||a||^2, ||g||^2, a.g
    float r0 = a * a, r1 = g * g, r2 = a * g;
    #pragma unroll
    for (int m = 1; m < 64; m <<= 1) {
        r0 += __shfl_xor(r0, m);
        r1 += __shfl_xor(r1, m);
        r2 += __shfl_xor(r2, m);
    }
    __shared__ float red[4][3];
    if (lane == 0) { red[w][0] = r0; red[w][1] = r1; red[w][2] = r2; }
    __syncthreads();
    if (tid == 0) {
        float a2 = red[0][0] + red[1][0] + red[2][0] + red[3][0];
        float g2 = red[0][1] + red[1][1] + red[2][1] + red[3][1];
        float ag = red[0][2] + red[1][2] + red[2][2] + red[3][2];
        float an = sqrtf(a2), gn = sqrtf(g2);
        float cs = (c > 0) ? (ag / (fmaxf(an, 1e-12f) * fmaxf(gn, 1e-12f))) : 0.f;
        cos_ws[i] = cs;
    }

    // logits: concat(g, a) @ Wc + bc
    float lg[TT];
    #pragma unroll
    for (int t = 0; t < TT; ++t)
        lg[t] = g * Wc[(size_t)tid * TT + t] + a * Wc[(size_t)(D + tid) * TT + t];
    #pragma unroll
    for (int m = 1; m < 64; m <<= 1)
        #pragma unroll
        for (int t = 0; t < TT; ++t) lg[t] += __shfl_xor(lg[t], m);
    __shared__ float lpart[4][TT];
    if (lane == 0)
        #pragma unroll
        for (int t = 0; t < TT; ++t) lpart[w][t] = lg[t];
    __syncthreads();
    if (tid < TT)
        logits[(size_t)i * TT + tid] =
            lpart[0][tid] + lpart[1][tid] + lpart[2][tid] + lpart[3][tid] + bc[tid];
}

// ---------------------------------------------------------------------------
// K3: cosine loss = 1 - mean(cos)
// ---------------------------------------------------------------------------
__global__ void loss_kernel(const float* __restrict__ cos_ws,
                            float* __restrict__ out, int B)
{
    const int lane = threadIdx.x;   // 64 threads
    float s = 0.f;
    for (int i = lane; i < B; i += 64) s += cos_ws[i];
    #pragma unroll
    for (int m = 1; m < 64; m <<= 1) s += __shfl_xor(s, m);
    if (lane == 0) out[0] = 1.0f - s / (float)B;
}

// ---------------------------------------------------------------------------
extern "C" void kernel_launch(void* const* d_in, const int* in_sizes, int n_in,
                              void* d_out, int out_size, void* d_ws, size_t ws_size,
                              hipStream_t stream)
{
    const float* h_graph = (const float*)d_in[0];
    const float* h_sub   = (const float*)d_in[1];
    const float* W1      = (const float*)d_in[2];
    const float* b1      = (const float*)d_in[3];
    const float* W2      = (const float*)d_in[4];
    const float* b2      = (const float*)d_in[5];
    const float* Wc      = (const float*)d_in[6];
    const float* bc      = (const float*)d_in[7];
    const int*   mask    = (const int*)d_in[8];

    const int B = in_sizes[0] / D;
    const int S = in_sizes[1] / D;

    float* out     = (float*)d_out;
    float* logits  = out;                       // [B*TT]
    float* loss    = out + (size_t)B * TT;      // [1]
    float* submask = loss + 1;                  // [S]
    float* cos_ws  = (float*)d_ws;              // [B] scratch

    gate_kernel<<<S / JT, 256, JT * D * sizeof(float), stream>>>(
        h_sub, W1, b1, W2, b2, submask);
    seg_kernel<<<B, 256, 0, stream>>>(
        h_graph, h_sub, mask, submask, Wc, bc, logits, cos_ws, S);
    loss_kernel<<<1, 64, 0, stream>>>(cos_ws, loss, B);
}

// Round 2
// 180.363 us; speedup vs baseline: 1.7812x; 1.7812x over previous
//
#include <hip/hip_runtime.h>
#include <math.h>

#define D 256
#define H 512
#define TT 10
#define THRESH 0.4f
#define MT 128        // rows per gate block
#define NCHUNK 2      // n_tiles (16 cols each) per LDS stage chunk
#define NT_TOTAL 32   // H / 16
#define KS 8          // K steps of 32 (D = 256)

typedef __attribute__((ext_vector_type(8))) short bf16x8;
typedef __attribute__((ext_vector_type(4))) float f32x4;

__device__ inline short f2bf(float x) {
    unsigned u = __builtin_bit_cast(unsigned, x);
    u += 0x7FFFu + ((u >> 16) & 1u);
    return (short)(u >> 16);
}
__device__ inline float bf2f(short h) {
    unsigned u = ((unsigned)(unsigned short)h) << 16;
    return __builtin_bit_cast(float, u);
}

// ---------------------------------------------------------------------------
// K0: swizzle W1 [D][H] f32 -> hi/lo bf16 MFMA B-fragments in ws.
// layout (shorts): off = (((n*2 + hl)*8 + k)*64 + lane)*8 + i
//   value = W1[k*32 + (lane>>4)*8 + i][n*16 + (lane&15)]
// ---------------------------------------------------------------------------
__global__ __launch_bounds__(256) void w1_prep(const float* __restrict__ W1,
                                               short* __restrict__ W1s)
{
    const int tid = blockIdx.x * 256 + threadIdx.x;   // 16384 threads
    const int lane = tid & 63;
    const int cell = tid >> 6;                        // 0..255 = (n,k)
    const int k = cell & 7;
    const int n = cell >> 3;
    const int row0 = k * 32 + (lane >> 4) * 8;
    const int col = n * 16 + (lane & 15);
    short hi8[8], lo8[8];
    #pragma unroll
    for (int i = 0; i < 8; ++i) {
        float x = W1[(size_t)(row0 + i) * H + col];
        short h = f2bf(x);
        hi8[i] = h;
        lo8[i] = f2bf(x - bf2f(h));
    }
    size_t bh = ((((size_t)n * 2 + 0) * 8 + k) * 64 + lane) * 8;
    size_t bl = ((((size_t)n * 2 + 1) * 8 + k) * 64 + lane) * 8;
    *reinterpret_cast<bf16x8*>(W1s + bh) = *reinterpret_cast<bf16x8*>(hi8);
    *reinterpret_cast<bf16x8*>(W1s + bl) = *reinterpret_cast<bf16x8*>(lo8);
}

// ---------------------------------------------------------------------------
// K1: gate MLP via split-bf16 MFMA.
// block = 256 thr (4 waves); wave w owns rows w*32..w*32+31 as A-frags in reg.
// W1 fragments streamed through double-buffered LDS (2 n_tiles per chunk).
// ---------------------------------------------------------------------------
__global__ __launch_bounds__(256, 2) void gate_mfma(
    const float* __restrict__ h_sub,
    const short* __restrict__ W1s,
    const float* __restrict__ b1,
    const float* __restrict__ W2,
    const float* __restrict__ b2,
    float* __restrict__ submask)
{
    __shared__ __align__(16) short sW[2][NCHUNK][2][KS][64][8];  // 64 KB
    __shared__ float sb1[H], sw2[H];
    const int tid = threadIdx.x;
    const int lane = tid & 63;
    const int w = tid >> 6;
    const int base = blockIdx.x * MT;

    // stage b1 / W2 (f32) into LDS
    {
        int i = tid * 2;
        *reinterpret_cast<float2*>(&sb1[i]) = *reinterpret_cast<const float2*>(&b1[i]);
        *reinterpret_cast<float2*>(&sw2[i]) = *reinterpret_cast<const float2*>(&W2[i]);
    }

    // load this wave's 32 rows of h_sub as hi/lo bf16 A-fragments (128 VGPR)
    bf16x8 ahi[2][KS], alo[2][KS];
    #pragma unroll
    for (int s = 0; s < 2; ++s) {
        const int row = base + w * 32 + s * 16 + (lane & 15);
        const float* rp = h_sub + (size_t)row * D + (lane >> 4) * 8;
        #pragma unroll
        for (int k = 0; k < KS; ++k) {
            float x[8];
            *reinterpret_cast<float4*>(&x[0]) =
                *reinterpret_cast<const float4*>(rp + k * 32);
            *reinterpret_cast<float4*>(&x[4]) =
                *reinterpret_cast<const float4*>(rp + k * 32 + 4);
            short hi8[8], lo8[8];
            #pragma unroll
            for (int i = 0; i < 8; ++i) {
                short h = f2bf(x[i]);
                hi8[i] = h;
                lo8[i] = f2bf(x[i] - bf2f(h));
            }
            ahi[s][k] = *reinterpret_cast<bf16x8*>(hi8);
            alo[s][k] = *reinterpret_cast<bf16x8*>(lo8);
        }
    }

    // chunk staging: 32 KB per chunk, reg-staged (issue early, write late)
    float4 stg[8];
    const int NCH = NT_TOTAL / NCHUNK;  // 16 chunks
    auto issue = [&](int c) {
        const float4* src = reinterpret_cast<const float4*>(W1s + (size_t)c * 16384);
        #pragma unroll
        for (int i = 0; i < 8; ++i) stg[i] = src[i * 256 + tid];
    };
    auto commit = [&](int buf) {
        float4* dst = reinterpret_cast<float4*>(&sW[buf][0][0][0][0][0]);
        #pragma unroll
        for (int i = 0; i < 8; ++i) dst[i * 256 + tid] = stg[i];
    };

    float lp[2][4] = {{0.f,0.f,0.f,0.f},{0.f,0.f,0.f,0.f}};

    issue(0);
    commit(0);
    for (int c = 0; c < NCH; ++c) {
        if (c + 1 < NCH) issue(c + 1);
        __syncthreads();                       // buf[c&1] visible to all waves
        #pragma unroll
        for (int t = 0; t < NCHUNK; ++t) {
            const int n = c * NCHUNK + t;
            f32x4 a0[2], a1[2], a2[2];
            #pragma unroll
            for (int s = 0; s < 2; ++s) {
                a0[s] = (f32x4){0.f,0.f,0.f,0.f};
                a1[s] = (f32x4){0.f,0.f,0.f,0.f};
                a2[s] = (f32x4){0.f,0.f,0.f,0.f};
            }
            #pragma unroll
            for (int k = 0; k < KS; ++k) {
                bf16x8 bh = *reinterpret_cast<const bf16x8*>(&sW[c & 1][t][0][k][lane][0]);
                bf16x8 bl = *reinterpret_cast<const bf16x8*>(&sW[c & 1][t][1][k][lane][0]);
                #pragma unroll
                for (int s = 0; s < 2; ++s) {
                    a0[s] = __builtin_amdgcn_mfma_f32_16x16x32_bf16(ahi[s][k], bh, a0[s], 0, 0, 0);
                    a1[s] = __builtin_amdgcn_mfma_f32_16x16x32_bf16(ahi[s][k], bl, a1[s], 0, 0, 0);
                    a2[s] = __builtin_amdgcn_mfma_f32_16x16x32_bf16(alo[s][k], bh, a2[s], 0, 0, 0);
                }
            }
            // epilogue for these 16 hidden cols: +b1, relu, dot W2
            const int h = n * 16 + (lane & 15);
            const float b1h = sb1[h], w2h = sw2[h];
            #pragma unroll
            for (int s = 0; s < 2; ++s)
                #pragma unroll
                for (int j = 0; j < 4; ++j) {
                    float v = a0[s][j] + a1[s][j] + a2[s][j] + b1h;
                    v = v > 0.f ? v : 0.f;
                    lp[s][j] = fmaf(v, w2h, lp[s][j]);
                }
        }
        __syncthreads();                       // all waves done with buf[(c+1)&1]
        if (c + 1 < NCH) commit((c + 1) & 1);
    }

    // reduce partial logits over the 16 cols (lanes within each 16-lane group)
    #pragma unroll
    for (int m = 1; m < 16; m <<= 1)
        #pragma unroll
        for (int s = 0; s < 2; ++s)
            #pragma unroll
            for (int j = 0; j < 4; ++j)
                lp[s][j] += __shfl_xor(lp[s][j], m);

    if ((lane & 15) == 0) {
        const float bb = b2[0];
        const int g = lane >> 4;
        #pragma unroll
        for (int s = 0; s < 2; ++s)
            #pragma unroll
            for (int j = 0; j < 4; ++j) {
                float logit = lp[s][j] + bb;
                submask[base + w * 32 + s * 16 + g * 4 + j] =
                    1.f / (1.f + expf(-logit));
            }
    }
}

// ---------------------------------------------------------------------------
// K2: per-graph masked segment mean + cosine + classifier logits
// ---------------------------------------------------------------------------
__global__ __launch_bounds__(256) void seg_kernel(
    const float* __restrict__ h_graph,  // [B][D]
    const float* __restrict__ h_sub,    // [S][D]
    const int*   __restrict__ mask,     // [B][S]
    const float* __restrict__ submask,  // [S]
    const float* __restrict__ Wc,       // [2D][TT]
    const float* __restrict__ bc,       // [TT]
    float* __restrict__ logits,         // [B][TT]
    float* __restrict__ cos_ws,         // [B]
    int S)
{
    const int i = blockIdx.x;
    const int tid = threadIdx.x;
    const int lane = tid & 63;
    const int w = tid >> 6;
    const int* mrow = mask + (size_t)i * S;

    float4 acc = make_float4(0.f, 0.f, 0.f, 0.f);
    int cnt = 0;

    const int per = S >> 2;
    for (int base = w * per; base < (w + 1) * per; base += 256) {
        const int j0 = base + (lane << 2);
        int4 m4 = *reinterpret_cast<const int4*>(mrow + j0);
        unsigned long long bal[4];
        bal[0] = __ballot((m4.x != 0) & (submask[j0 + 0] > THRESH));
        bal[1] = __ballot((m4.y != 0) & (submask[j0 + 1] > THRESH));
        bal[2] = __ballot((m4.z != 0) & (submask[j0 + 2] > THRESH));
        bal[3] = __ballot((m4.w != 0) & (submask[j0 + 3] > THRESH));
        #pragma unroll
        for (int s = 0; s < 4; ++s) {
            unsigned long long b = bal[s];
            while (b) {
                int t = __builtin_ctzll(b);
                b &= b - 1;
                int jj = base + (t << 2) + s;
                float4 hv = *reinterpret_cast<const float4*>(
                    h_sub + (size_t)jj * D + (lane << 2));
                acc.x += hv.x; acc.y += hv.y; acc.z += hv.z; acc.w += hv.w;
                cnt++;
            }
        }
    }

    __shared__ float ssum[4][D];
    __shared__ int   scnt[4];
    *reinterpret_cast<float4*>(&ssum[w][lane << 2]) = acc;
    if (lane == 0) scnt[w] = cnt;
    __syncthreads();

    float a = ssum[0][tid] + ssum[1][tid] + ssum[2][tid] + ssum[3][tid];
    const int c = scnt[0] + scnt[1] + scnt[2] + scnt[3];
    a = (c > 0) ? (a / (float)c) : 0.f;
    const float g = h_graph[(size_t)i * D + tid];

    float r0 = a * a, r1 = g * g, r2 = a * g;
    #pragma unroll
    for (int m = 1; m < 64; m <<= 1) {
        r0 += __shfl_xor(r0, m);
        r1 += __shfl_xor(r1, m);
        r2 += __shfl_xor(r2, m);
    }
    __shared__ float red[4][3];
    if (lane == 0) { red[w][0] = r0; red[w][1] = r1; red[w][2] = r2; }
    __syncthreads();
    if (tid == 0) {
        float a2 = red[0][0] + red[1][0] + red[2][0] + red[3][0];
        float g2 = red[0][1] + red[1][1] + red[2][1] + red[3][1];
        float ag = red[0][2] + red[1][2] + red[2][2] + red[3][2];
        float an = sqrtf(a2), gn = sqrtf(g2);
        float cs = (c > 0) ? (ag / (fmaxf(an, 1e-12f) * fmaxf(gn, 1e-12f))) : 0.f;
        cos_ws[i] = cs;
    }

    float lg[TT];
    #pragma unroll
    for (int t = 0; t < TT; ++t)
        lg[t] = g * Wc[(size_t)tid * TT + t] + a * Wc[(size_t)(D + tid) * TT + t];
    #pragma unroll
    for (int m = 1; m < 64; m <<= 1)
        #pragma unroll
        for (int t = 0; t < TT; ++t) lg[t] += __shfl_xor(lg[t], m);
    __shared__ float lpart[4][TT];
    if (lane == 0)
        #pragma unroll
        for (int t = 0; t < TT; ++t) lpart[w][t] = lg[t];
    __syncthreads();
    if (tid < TT)
        logits[(size_t)i * TT + tid] =
            lpart[0][tid] + lpart[1][tid] + lpart[2][tid] + lpart[3][tid] + bc[tid];
}

// ---------------------------------------------------------------------------
__global__ void loss_kernel(const float* __restrict__ cos_ws,
                            float* __restrict__ out, int B)
{
    const int lane = threadIdx.x;
    float s = 0.f;
    for (int i = lane; i < B; i += 64) s += cos_ws[i];
    #pragma unroll
    for (int m = 1; m < 64; m <<= 1) s += __shfl_xor(s, m);
    if (lane == 0) out[0] = 1.0f - s / (float)B;
}

// ---------------------------------------------------------------------------
extern "C" void kernel_launch(void* const* d_in, const int* in_sizes, int n_in,
                              void* d_out, int out_size, void* d_ws, size_t ws_size,
                              hipStream_t stream)
{
    const float* h_graph = (const float*)d_in[0];
    const float* h_sub   = (const float*)d_in[1];
    const float* W1      = (const float*)d_in[2];
    const float* b1      = (const float*)d_in[3];
    const float* W2      = (const float*)d_in[4];
    const float* b2      = (const float*)d_in[5];
    const float* Wc      = (const float*)d_in[6];
    const float* bc      = (const float*)d_in[7];
    const int*   mask    = (const int*)d_in[8];

    const int B = in_sizes[0] / D;
    const int S = in_sizes[1] / D;

    float* out     = (float*)d_out;
    float* logits  = out;                       // [B*TT]
    float* loss    = out + (size_t)B * TT;      // [1]
    float* submask = loss + 1;                  // [S]

    short* W1s    = (short*)d_ws;                            // 512 KB fragments
    float* cos_ws = (float*)((char*)d_ws + 600 * 1024);      // [B] scratch

    w1_prep<<<64, 256, 0, stream>>>(W1, W1s);
    gate_mfma<<<S / MT, 256, 0, stream>>>(h_sub, W1s, b1, W2, b2, submask);
    seg_kernel<<<B, 256, 0, stream>>>(
        h_graph, h_sub, mask, submask, Wc, bc, logits, cos_ws, S);
    loss_kernel<<<1, 64, 0, stream>>>(cos_ws, loss, B);
}